// Round 1
// baseline (2258.573 us; speedup 1.0000x reference)
//
#include <hip/hip_runtime.h>

// MoE: B=4,S=2048,D=1024,E=8,H=4096,K=2.  T = B*S = 8192 tokens.
// Sparse dispatch: token->top2 experts, per-expert gathered GEMMs in bf16 MFMA.
// ws usage ~195.4 MB.

#define T_TOK 8192
#define DDIM 1024
#define EEXP 8
#define HDIM 4096
#define RMAX 17408   // T*K + E*128 padding

typedef short short8 __attribute__((ext_vector_type(8)));
typedef float f32x4 __attribute__((ext_vector_type(4)));
typedef unsigned short ushort4v __attribute__((ext_vector_type(4)));

__device__ __forceinline__ unsigned short f2bf(float f) {
  unsigned u = __builtin_bit_cast(unsigned, f);
  return (unsigned short)((u + 0x7FFFu + ((u >> 16) & 1u)) >> 16);
}
__device__ __forceinline__ float bf2f(unsigned short b) {
  unsigned u = ((unsigned)b) << 16;
  return __builtin_bit_cast(float, u);
}

// ---- x -> bf16 -------------------------------------------------------------
__global__ void k_convert_x(const float* __restrict__ x, unsigned short* __restrict__ xb) {
  int i = blockIdx.x * 256 + threadIdx.x;   // 4 elems each, grid sized exactly
  float4 v = ((const float4*)x)[i];
  ushort4v o;
  o.x = f2bf(v.x); o.y = f2bf(v.y); o.z = f2bf(v.z); o.w = f2bf(v.w);
  *(ushort4v*)(xb + (size_t)i * 4) = o;
}

// ---- init ------------------------------------------------------------------
__global__ void k_init(int* __restrict__ rowtok, int* __restrict__ counts, int* __restrict__ cursor) {
  int i = blockIdx.x * 256 + threadIdx.x;
  if (i < RMAX) rowtok[i] = 0;
  if (i < EEXP) { counts[i] = 0; cursor[i] = 0; }
}

// ---- gating: logits, noisy top-2, softmax, counts --------------------------
__launch_bounds__(256)
__global__ void k_gate(const float* __restrict__ x, const float* __restrict__ gw,
                       const float* __restrict__ nwt, const float* __restrict__ noi,
                       int* __restrict__ tki, float* __restrict__ tkp,
                       int* __restrict__ counts) {
  __shared__ float gwT[8][1024];
  int tid = threadIdx.x;
#pragma unroll
  for (int q = 0; q < 32; q++) {
    int flat = q * 256 + tid;           // 8192 = D*E
    gwT[flat & 7][flat >> 3] = gw[flat];
  }
  __syncthreads();
  int wave = tid >> 6, l = tid & 63;
  int t = blockIdx.x * 4 + wave;
  float acc[8] = {0.f, 0.f, 0.f, 0.f, 0.f, 0.f, 0.f, 0.f};
  const float4* xr = (const float4*)(x + (size_t)t * DDIM);
#pragma unroll
  for (int i = 0; i < 4; i++) {
    float4 xv = xr[l + i * 64];
    int d0 = (l + i * 64) * 4;
#pragma unroll
    for (int e = 0; e < 8; e++) {
      float4 gv = *(const float4*)&gwT[e][d0];
      acc[e] += xv.x * gv.x + xv.y * gv.y + xv.z * gv.z + xv.w * gv.w;
    }
  }
#pragma unroll
  for (int s = 1; s < 64; s <<= 1) {
#pragma unroll
    for (int e = 0; e < 8; e++) acc[e] += __shfl_xor(acc[e], s, 64);
  }
  if (l == 0) {
    float nl[8];
#pragma unroll
    for (int e = 0; e < 8; e++) nl[e] = acc[e] + noi[t * 8 + e] * nwt[e];
    int i0 = 0; float v0 = nl[0];
#pragma unroll
    for (int e = 1; e < 8; e++) if (nl[e] > v0) { v0 = nl[e]; i0 = e; }
    int i1 = -1; float v1 = -3.4e38f;
#pragma unroll
    for (int e = 0; e < 8; e++) if (e != i0 && nl[e] > v1) { v1 = nl[e]; i1 = e; }
    float ex = __expf(v1 - v0);
    float p0 = 1.f / (1.f + ex);
    float p1 = ex * p0;
    tki[2 * t] = i0; tki[2 * t + 1] = i1;
    tkp[2 * t] = p0; tkp[2 * t + 1] = p1;
    atomicAdd(&counts[i0], 1);
    atomicAdd(&counts[i1], 1);
  }
}

// ---- prefix (padded to 128-row tiles) --------------------------------------
__global__ void k_prefix(const int* __restrict__ counts, int* __restrict__ basep) {
  if (threadIdx.x == 0) {
    int b = 0;
    for (int e = 0; e < EEXP; e++) { basep[e] = b; b += (counts[e] + 127) & ~127; }
  }
}

// ---- scatter tokens to rows ------------------------------------------------
__global__ void k_scatter(const int* __restrict__ tki, const int* __restrict__ basep,
                          int* __restrict__ cursor, int* __restrict__ rowtok,
                          int* __restrict__ t2r) {
  int t = blockIdx.x * 256 + threadIdx.x;
  if (t >= T_TOK) return;
#pragma unroll
  for (int k = 0; k < 2; k++) {
    int e = tki[2 * t + k];
    int pos = atomicAdd(&cursor[e], 1);
    int row = basep[e] + pos;
    rowtok[row] = t;
    t2r[2 * t + k] = row;
  }
}

// ---- GEMM1: h = (Xg @ w1 + b1) * silu(Xg @ w2 + b2), bf16 out --------------
__launch_bounds__(256, 2)
__global__ void k_gemm1(const unsigned short* __restrict__ xb,
                        const float* __restrict__ w1g, const float* __restrict__ w2g,
                        const float* __restrict__ b1g, const float* __restrict__ b2g,
                        const int* __restrict__ counts, const int* __restrict__ basep,
                        const int* __restrict__ rowtok,
                        unsigned short* __restrict__ hout) {
  int e = blockIdx.y >> 6;
  int rt = blockIdx.y & 63;
  int cnt = counts[e];
  if (rt >= ((cnt + 127) >> 7)) return;
  int ct = blockIdx.x;              // 0..31 over H
  int row0 = basep[e] + rt * 128;
  int col0 = ct * 128;

  __shared__ char smem[49152];      // As[128][64] | B1t[128][64] | B2t[128][64] (bf16, swizzled)
  __shared__ int s_tok[128];
  __shared__ float s_b1[128], s_b2[128];

  int tid = threadIdx.x;
  if (tid < 128) {
    s_tok[tid] = rowtok[row0 + tid];
    s_b1[tid] = b1g[e * HDIM + col0 + tid];
    s_b2[tid] = b2g[e * HDIM + col0 + tid];
  }
  __syncthreads();

  int wave = tid >> 6, l = tid & 63;
  int wr = (wave >> 1) << 6, wc = (wave & 1) << 6;
  int g = l >> 4, ln = l & 15;

  f32x4 zero = {0.f, 0.f, 0.f, 0.f};
  f32x4 acc_a[4][4], acc_b[4][4];
#pragma unroll
  for (int m = 0; m < 4; m++)
#pragma unroll
    for (int n = 0; n < 4; n++) { acc_a[m][n] = zero; acc_b[m][n] = zero; }

  const float* w1e = w1g + (size_t)e * DDIM * HDIM + col0;
  const float* w2e = w2g + (size_t)e * DDIM * HDIM + col0;

  for (int kt = 0; kt < DDIM / 64; kt++) {
    // stage A (gathered x rows, bf16 vector loads)
#pragma unroll
    for (int q = 0; q < 4; q++) {
      int flat = q * 256 + tid;
      int r = flat >> 3, c8 = (flat & 7) << 3;
      int tok = s_tok[r];
      short8 v = *(const short8*)(xb + (size_t)tok * DDIM + kt * 64 + c8);
      int byte = (r * 128 + c8 * 2) ^ ((r & 7) << 4);
      *(short8*)(smem + byte) = v;
    }
    // stage B1/B2 (f32 -> bf16, transposed into [n][k])
#pragma unroll
    for (int q = 0; q < 8; q++) {
      int flat = (q * 256 + tid) * 4;
      int kr = flat >> 7, c = flat & 127;
      float4 v1 = *(const float4*)(w1e + (size_t)(kt * 64 + kr) * HDIM + c);
      float4 v2 = *(const float4*)(w2e + (size_t)(kt * 64 + kr) * HDIM + c);
      float a1[4] = {v1.x, v1.y, v1.z, v1.w};
      float a2[4] = {v2.x, v2.y, v2.z, v2.w};
#pragma unroll
      for (int i = 0; i < 4; i++) {
        int n = c + i;
        int byte = (n * 128 + kr * 2) ^ ((n & 7) << 4);
        *(unsigned short*)(smem + 16384 + byte) = f2bf(a1[i]);
        *(unsigned short*)(smem + 32768 + byte) = f2bf(a2[i]);
      }
    }
    __syncthreads();
#pragma unroll
    for (int ks = 0; ks < 2; ks++) {
      int kb = ks * 64 + g * 16;
      short8 af[4], bf1[4], bf2[4];
#pragma unroll
      for (int m = 0; m < 4; m++) {
        int r = wr + m * 16 + ln;
        af[m] = *(const short8*)(smem + ((r * 128 + kb) ^ ((r & 7) << 4)));
      }
#pragma unroll
      for (int n = 0; n < 4; n++) {
        int r = wc + n * 16 + ln;
        int byte = (r * 128 + kb) ^ ((r & 7) << 4);
        bf1[n] = *(const short8*)(smem + 16384 + byte);
        bf2[n] = *(const short8*)(smem + 32768 + byte);
      }
#pragma unroll
      for (int m = 0; m < 4; m++)
#pragma unroll
        for (int n = 0; n < 4; n++) {
          acc_a[m][n] = __builtin_amdgcn_mfma_f32_16x16x32_bf16(af[m], bf1[n], acc_a[m][n], 0, 0, 0);
          acc_b[m][n] = __builtin_amdgcn_mfma_f32_16x16x32_bf16(af[m], bf2[n], acc_b[m][n], 0, 0, 0);
        }
    }
    __syncthreads();
  }
  // epilogue: SwiGLU -> bf16 tile in LDS, then coalesced stores
  unsigned short* ht = (unsigned short*)smem;
#pragma unroll
  for (int m = 0; m < 4; m++)
#pragma unroll
    for (int n = 0; n < 4; n++)
#pragma unroll
      for (int r = 0; r < 4; r++) {
        int row = wr + m * 16 + g * 4 + r;
        int col = wc + n * 16 + ln;
        float a = acc_a[m][n][r] + s_b1[col];
        float b = acc_b[m][n][r] + s_b2[col];
        float hv = a * (b / (1.f + __expf(-b)));
        ht[row * 128 + col] = f2bf(hv);
      }
  __syncthreads();
#pragma unroll
  for (int q = 0; q < 8; q++) {
    int idx = q * 256 + tid;          // 16B chunks, 2048 total
    int row = idx >> 4, chunk = idx & 15;
    short8 v = *(const short8*)(smem + idx * 16);
    *(short8*)(hout + (size_t)(row0 + row) * HDIM + col0 + chunk * 8) = v;
  }
}

// ---- GEMM2: y = h @ wp + bp (bf16 out, unscaled) ---------------------------
__launch_bounds__(256, 2)
__global__ void k_gemm2(const unsigned short* __restrict__ hin,
                        const float* __restrict__ wpg, const float* __restrict__ bpg,
                        const int* __restrict__ counts, const int* __restrict__ basep,
                        unsigned short* __restrict__ yout) {
  int e = blockIdx.y >> 6;
  int rt = blockIdx.y & 63;
  int cnt = counts[e];
  if (rt >= ((cnt + 127) >> 7)) return;
  int ct = blockIdx.x;              // 0..7 over D
  int row0 = basep[e] + rt * 128;
  int col0 = ct * 128;

  __shared__ char smem[32768];      // As[128][64] | Bt[128][64]
  __shared__ float s_bp[128];
  int tid = threadIdx.x;
  if (tid < 128) s_bp[tid] = bpg[e * DDIM + col0 + tid];

  int wave = tid >> 6, l = tid & 63;
  int wr = (wave >> 1) << 6, wc = (wave & 1) << 6;
  int g = l >> 4, ln = l & 15;

  f32x4 zero = {0.f, 0.f, 0.f, 0.f};
  f32x4 acc[4][4];
#pragma unroll
  for (int m = 0; m < 4; m++)
#pragma unroll
    for (int n = 0; n < 4; n++) acc[m][n] = zero;

  const float* wpe = wpg + (size_t)e * HDIM * DDIM + col0;

  for (int kt = 0; kt < HDIM / 64; kt++) {
#pragma unroll
    for (int q = 0; q < 4; q++) {
      int flat = q * 256 + tid;
      int r = flat >> 3, c8 = (flat & 7) << 3;
      short8 v = *(const short8*)(hin + (size_t)(row0 + r) * HDIM + kt * 64 + c8);
      int byte = (r * 128 + c8 * 2) ^ ((r & 7) << 4);
      *(short8*)(smem + byte) = v;
    }
#pragma unroll
    for (int q = 0; q < 8; q++) {
      int flat = (q * 256 + tid) * 4;
      int kr = flat >> 7, c = flat & 127;
      float4 v = *(const float4*)(wpe + (size_t)(kt * 64 + kr) * DDIM + c);
      float a[4] = {v.x, v.y, v.z, v.w};
#pragma unroll
      for (int i = 0; i < 4; i++) {
        int n = c + i;
        int byte = (n * 128 + kr * 2) ^ ((n & 7) << 4);
        *(unsigned short*)(smem + 16384 + byte) = f2bf(a[i]);
      }
    }
    __syncthreads();
#pragma unroll
    for (int ks = 0; ks < 2; ks++) {
      int kb = ks * 64 + g * 16;
      short8 af[4], bf[4];
#pragma unroll
      for (int m = 0; m < 4; m++) {
        int r = wr + m * 16 + ln;
        af[m] = *(const short8*)(smem + ((r * 128 + kb) ^ ((r & 7) << 4)));
      }
#pragma unroll
      for (int n = 0; n < 4; n++) {
        int r = wc + n * 16 + ln;
        bf[n] = *(const short8*)(smem + 16384 + ((r * 128 + kb) ^ ((r & 7) << 4)));
      }
#pragma unroll
      for (int m = 0; m < 4; m++)
#pragma unroll
        for (int n = 0; n < 4; n++)
          acc[m][n] = __builtin_amdgcn_mfma_f32_16x16x32_bf16(af[m], bf[n], acc[m][n], 0, 0, 0);
    }
    __syncthreads();
  }
  unsigned short* ht = (unsigned short*)smem;
#pragma unroll
  for (int m = 0; m < 4; m++)
#pragma unroll
    for (int n = 0; n < 4; n++)
#pragma unroll
      for (int r = 0; r < 4; r++) {
        int row = wr + m * 16 + g * 4 + r;
        int col = wc + n * 16 + ln;
        ht[row * 128 + col] = f2bf(acc[m][n][r] + s_bp[col]);
      }
  __syncthreads();
#pragma unroll
  for (int q = 0; q < 8; q++) {
    int idx = q * 256 + tid;
    int row = idx >> 4, chunk = idx & 15;
    short8 v = *(const short8*)(smem + idx * 16);
    *(short8*)(yout + (size_t)(row0 + row) * DDIM + col0 + chunk * 8) = v;
  }
}

// ---- combine: out[t] = p0*y[r0] + p1*y[r1] ---------------------------------
__global__ void k_combine(const unsigned short* __restrict__ yv,
                          const int* __restrict__ t2r, const float* __restrict__ tkp,
                          float* __restrict__ outp) {
  int gid = blockIdx.x * 256 + threadIdx.x;
  int t = gid >> 8;
  int c4 = (gid & 255) << 2;
  int r0 = t2r[2 * t], r1 = t2r[2 * t + 1];
  float p0 = tkp[2 * t], p1 = tkp[2 * t + 1];
  ushort4v u0 = *(const ushort4v*)(yv + (size_t)r0 * DDIM + c4);
  ushort4v u1 = *(const ushort4v*)(yv + (size_t)r1 * DDIM + c4);
  float4 o;
  o.x = p0 * bf2f(u0.x) + p1 * bf2f(u1.x);
  o.y = p0 * bf2f(u0.y) + p1 * bf2f(u1.y);
  o.z = p0 * bf2f(u0.z) + p1 * bf2f(u1.z);
  o.w = p0 * bf2f(u0.w) + p1 * bf2f(u1.w);
  *(float4*)(outp + (size_t)t * DDIM + c4) = o;
}

extern "C" void kernel_launch(void* const* d_in, const int* in_sizes, int n_in,
                              void* d_out, int out_size, void* d_ws, size_t ws_size,
                              hipStream_t stream) {
  const float* x   = (const float*)d_in[0];
  const float* gw  = (const float*)d_in[1];
  const float* nwt = (const float*)d_in[2];
  const float* noi = (const float*)d_in[3];
  const float* w1  = (const float*)d_in[4];
  const float* b1  = (const float*)d_in[5];
  const float* w2  = (const float*)d_in[6];
  const float* b2  = (const float*)d_in[7];
  const float* wp  = (const float*)d_in[8];
  const float* bp  = (const float*)d_in[9];
  float* outp = (float*)d_out;
  char* ws = (char*)d_ws;

  constexpr size_t OFF_XB  = 0;
  constexpr size_t OFF_H   = OFF_XB + (size_t)T_TOK * DDIM * 2;   // 16,777,216
  constexpr size_t OFF_Y   = OFF_H + (size_t)RMAX * HDIM * 2;     // +142,606,336
  constexpr size_t OFF_RT  = OFF_Y + (size_t)RMAX * DDIM * 2;     // +35,651,584
  constexpr size_t OFF_TKI = OFF_RT + (size_t)RMAX * 4;
  constexpr size_t OFF_TKP = OFF_TKI + (size_t)T_TOK * 2 * 4;
  constexpr size_t OFF_T2R = OFF_TKP + (size_t)T_TOK * 2 * 4;
  constexpr size_t OFF_CNT = OFF_T2R + (size_t)T_TOK * 2 * 4;
  constexpr size_t OFF_BAS = OFF_CNT + 256;
  constexpr size_t OFF_CUR = OFF_BAS + 256;
  // total ~195.4 MB

  unsigned short* xb = (unsigned short*)(ws + OFF_XB);
  unsigned short* h  = (unsigned short*)(ws + OFF_H);
  unsigned short* y  = (unsigned short*)(ws + OFF_Y);
  int*   rowtok = (int*)(ws + OFF_RT);
  int*   tki    = (int*)(ws + OFF_TKI);
  float* tkp    = (float*)(ws + OFF_TKP);
  int*   t2r    = (int*)(ws + OFF_T2R);
  int*   counts = (int*)(ws + OFF_CNT);
  int*   basep  = (int*)(ws + OFF_BAS);
  int*   cursor = (int*)(ws + OFF_CUR);

  dim3 blk(256);
  k_convert_x<<<dim3((T_TOK * DDIM / 4) / 256), blk, 0, stream>>>(x, xb);
  k_init<<<dim3((RMAX + 255) / 256), blk, 0, stream>>>(rowtok, counts, cursor);
  k_gate<<<dim3(T_TOK / 4), blk, 0, stream>>>(x, gw, nwt, noi, tki, tkp, counts);
  k_prefix<<<dim3(1), dim3(64), 0, stream>>>(counts, basep);
  k_scatter<<<dim3(T_TOK / 256), blk, 0, stream>>>(tki, basep, cursor, rowtok, t2r);
  k_gemm1<<<dim3(HDIM / 128, EEXP * 64), blk, 0, stream>>>(xb, w1, w2, b1, b2, counts, basep, rowtok, h);
  k_gemm2<<<dim3(DDIM / 128, EEXP * 64), blk, 0, stream>>>(h, wp, bp, counts, basep, y);
  k_combine<<<dim3(T_TOK), blk, 0, stream>>>(y, t2r, tkp, outp);
  (void)in_sizes; (void)n_in; (void)out_size; (void)ws_size;
}

// Round 2
// 932.310 us; speedup vs baseline: 2.4226x; 2.4226x over previous
//
#include <hip/hip_runtime.h>

// MoE: B=4,S=2048,D=1024,E=8,H=4096,K=2.  T = B*S = 8192 tokens.
// R2: pre-convert weights to bf16, transposed [n][k], XOR-swizzled, 16KB tiles.
// GEMMs stage via global_load_lds (width 16), zero LDS-write conflicts.
// ws usage ~397 MB.

#define T_TOK 8192
#define DDIM 1024
#define EEXP 8
#define HDIM 4096
#define RMAX 17408   // T*K + E*128 padding

typedef short short8 __attribute__((ext_vector_type(8)));
typedef float f32x4 __attribute__((ext_vector_type(4)));
typedef unsigned short ushort4v __attribute__((ext_vector_type(4)));
typedef unsigned int u32;

__device__ __forceinline__ unsigned short f2bf(float f) {
  unsigned u = __builtin_bit_cast(unsigned, f);
  return (unsigned short)((u + 0x7FFFu + ((u >> 16) & 1u)) >> 16);
}
__device__ __forceinline__ float bf2f(unsigned short b) {
  unsigned u = ((unsigned)b) << 16;
  return __builtin_bit_cast(float, u);
}
__device__ __forceinline__ void gl_lds16(const void* g, void* l) {
  __builtin_amdgcn_global_load_lds((const u32 __attribute__((address_space(1)))*)g,
                                   (u32 __attribute__((address_space(3)))*)l, 16, 0, 0);
}

// ---- x -> bf16 -------------------------------------------------------------
__global__ void k_convert_x(const float* __restrict__ x, unsigned short* __restrict__ xb) {
  int i = blockIdx.x * 256 + threadIdx.x;
  float4 v = ((const float4*)x)[i];
  ushort4v o;
  o.x = f2bf(v.x); o.y = f2bf(v.y); o.z = f2bf(v.z); o.w = f2bf(v.w);
  *(ushort4v*)(xb + (size_t)i * 4) = o;
}

// ---- weights: f32 [E][K][N] -> bf16 swizzled tiles [E][ct][kt][16KB] -------
// Tile = 128 n x 64 k, content byte (n*128 + kc*16) ^ ((n&7)<<4) holds
// B^T[n][k=kc*8..+7].  Linear global_load_lds of the tile reproduces the
// swizzled LDS image the GEMM's ds_read expects.
__global__ void k_convert_w(const float* __restrict__ src, unsigned short* __restrict__ dst,
                            int N, int K) {
  __shared__ float lbuf[64 * 129];
  int e = blockIdx.z, ct = blockIdx.x, kt = blockIdx.y;
  int tid = threadIdx.x;
  const float* s = src + (size_t)e * K * N + (size_t)(kt * 64) * N + ct * 128;
#pragma unroll
  for (int q = 0; q < 8; q++) {
    int idx = q * 256 + tid;
    int row = idx >> 5, c4 = (idx & 31) * 4;
    float4 v = *(const float4*)(s + (size_t)row * N + c4);
    lbuf[row * 129 + c4 + 0] = v.x;
    lbuf[row * 129 + c4 + 1] = v.y;
    lbuf[row * 129 + c4 + 2] = v.z;
    lbuf[row * 129 + c4 + 3] = v.w;
  }
  __syncthreads();
  unsigned short* dt = dst + ((size_t)(e * (N / 128) + ct) * (K / 64) + kt) * 8192;
#pragma unroll
  for (int q = 0; q < 4; q++) {
    int idx = q * 256 + tid;
    int kc = idx & 7, n = idx >> 3;
    short8 o;
#pragma unroll
    for (int j = 0; j < 8; j++) o[j] = (short)f2bf(lbuf[(kc * 8 + j) * 129 + n]);
    int byte = (n * 128 + kc * 16) ^ ((n & 7) << 4);
    *(short8*)((char*)dt + byte) = o;
  }
}

// ---- init ------------------------------------------------------------------
__global__ void k_init(int* __restrict__ rowtok, int* __restrict__ counts, int* __restrict__ cursor) {
  int i = blockIdx.x * 256 + threadIdx.x;
  if (i < RMAX) rowtok[i] = 0;
  if (i < EEXP) { counts[i] = 0; cursor[i] = 0; }
}

// ---- gating ----------------------------------------------------------------
__launch_bounds__(256)
__global__ void k_gate(const float* __restrict__ x, const float* __restrict__ gw,
                       const float* __restrict__ nwt, const float* __restrict__ noi,
                       int* __restrict__ tki, float* __restrict__ tkp,
                       int* __restrict__ counts) {
  __shared__ float gwT[8][1024];
  int tid = threadIdx.x;
#pragma unroll
  for (int q = 0; q < 32; q++) {
    int flat = q * 256 + tid;
    gwT[flat & 7][flat >> 3] = gw[flat];
  }
  __syncthreads();
  int wave = tid >> 6, l = tid & 63;
  int t = blockIdx.x * 4 + wave;
  float acc[8] = {0.f, 0.f, 0.f, 0.f, 0.f, 0.f, 0.f, 0.f};
  const float4* xr = (const float4*)(x + (size_t)t * DDIM);
#pragma unroll
  for (int i = 0; i < 4; i++) {
    float4 xv = xr[l + i * 64];
    int d0 = (l + i * 64) * 4;
#pragma unroll
    for (int e = 0; e < 8; e++) {
      float4 gv = *(const float4*)&gwT[e][d0];
      acc[e] += xv.x * gv.x + xv.y * gv.y + xv.z * gv.z + xv.w * gv.w;
    }
  }
#pragma unroll
  for (int s = 1; s < 64; s <<= 1) {
#pragma unroll
    for (int e = 0; e < 8; e++) acc[e] += __shfl_xor(acc[e], s, 64);
  }
  if (l == 0) {
    float nl[8];
#pragma unroll
    for (int e = 0; e < 8; e++) nl[e] = acc[e] + noi[t * 8 + e] * nwt[e];
    int i0 = 0; float v0 = nl[0];
#pragma unroll
    for (int e = 1; e < 8; e++) if (nl[e] > v0) { v0 = nl[e]; i0 = e; }
    int i1 = -1; float v1 = -3.4e38f;
#pragma unroll
    for (int e = 0; e < 8; e++) if (e != i0 && nl[e] > v1) { v1 = nl[e]; i1 = e; }
    float ex = __expf(v1 - v0);
    float p0 = 1.f / (1.f + ex);
    float p1 = ex * p0;
    tki[2 * t] = i0; tki[2 * t + 1] = i1;
    tkp[2 * t] = p0; tkp[2 * t + 1] = p1;
    atomicAdd(&counts[i0], 1);
    atomicAdd(&counts[i1], 1);
  }
}

// ---- prefix ----------------------------------------------------------------
__global__ void k_prefix(const int* __restrict__ counts, int* __restrict__ basep) {
  if (threadIdx.x == 0) {
    int b = 0;
    for (int e = 0; e < EEXP; e++) { basep[e] = b; b += (counts[e] + 127) & ~127; }
  }
}

// ---- scatter ---------------------------------------------------------------
__global__ void k_scatter(const int* __restrict__ tki, const int* __restrict__ basep,
                          int* __restrict__ cursor, int* __restrict__ rowtok,
                          int* __restrict__ t2r) {
  int t = blockIdx.x * 256 + threadIdx.x;
  if (t >= T_TOK) return;
#pragma unroll
  for (int k = 0; k < 2; k++) {
    int e = tki[2 * t + k];
    int pos = atomicAdd(&cursor[e], 1);
    int row = basep[e] + pos;
    rowtok[row] = t;
    t2r[2 * t + k] = row;
  }
}

// ---- GEMM1: h = (Xg @ w1 + b1) * silu(Xg @ w2 + b2), bf16 out --------------
__launch_bounds__(256, 2)
__global__ void k_gemm1(const unsigned short* __restrict__ xb,
                        const unsigned short* __restrict__ w1s, const unsigned short* __restrict__ w2s,
                        const float* __restrict__ b1g, const float* __restrict__ b2g,
                        const int* __restrict__ counts, const int* __restrict__ basep,
                        const int* __restrict__ rowtok,
                        unsigned short* __restrict__ hout) {
  int e = blockIdx.y >> 6;
  int rt = blockIdx.y & 63;
  int cnt = counts[e];
  if (rt >= ((cnt + 127) >> 7)) return;
  int ct = blockIdx.x;              // 0..31 over H
  int row0 = basep[e] + rt * 128;
  int col0 = ct * 128;

  __shared__ char smem[49152];      // A[128][64] | B1t | B2t (bf16, swizzled)
  __shared__ int s_tok[128];
  __shared__ float s_b1[128], s_b2[128];

  int tid = threadIdx.x;
  if (tid < 128) {
    s_tok[tid] = rowtok[row0 + tid];
    s_b1[tid] = b1g[e * HDIM + col0 + tid];
    s_b2[tid] = b2g[e * HDIM + col0 + tid];
  }
  __syncthreads();

  int wave = tid >> 6, l = tid & 63;
  int wr = (wave >> 1) << 6, wc = (wave & 1) << 6;
  int g = l >> 4, ln = l & 15;

  // per-thread staging geometry (constant across K-tiles)
  int sr[4], stok[4], sxor[4];
#pragma unroll
  for (int q = 0; q < 4; q++) {
    int flat = q * 256 + tid;
    sr[q] = flat;                        // dest chunk
    int r = flat >> 3, c = flat & 7;
    stok[q] = s_tok[r];
    sxor[q] = (c ^ (r & 7)) << 3;        // source element offset within row
  }

  f32x4 zero = {0.f, 0.f, 0.f, 0.f};
  f32x4 acc_a[4][4], acc_b[4][4];
#pragma unroll
  for (int m = 0; m < 4; m++)
#pragma unroll
    for (int n = 0; n < 4; n++) { acc_a[m][n] = zero; acc_b[m][n] = zero; }

  const unsigned short* w1t = w1s + ((size_t)(e * 32 + ct) * 16) * 8192;
  const unsigned short* w2t = w2s + ((size_t)(e * 32 + ct) * 16) * 8192;

  for (int kt = 0; kt < 16; kt++) {
#pragma unroll
    for (int q = 0; q < 4; q++) {
      gl_lds16(xb + (size_t)stok[q] * DDIM + kt * 64 + sxor[q], smem + sr[q] * 16);
      gl_lds16(w1t + (size_t)kt * 8192 + sr[q] * 8, smem + 16384 + sr[q] * 16);
      gl_lds16(w2t + (size_t)kt * 8192 + sr[q] * 8, smem + 32768 + sr[q] * 16);
    }
    __syncthreads();
#pragma unroll
    for (int ks = 0; ks < 2; ks++) {
      int kb = ks * 64 + g * 16;
      short8 af[4], bf1[4], bf2[4];
#pragma unroll
      for (int m = 0; m < 4; m++) {
        int r = wr + m * 16 + ln;
        af[m] = *(const short8*)(smem + ((r * 128 + kb) ^ ((r & 7) << 4)));
      }
#pragma unroll
      for (int n = 0; n < 4; n++) {
        int r = wc + n * 16 + ln;
        int byte = (r * 128 + kb) ^ ((r & 7) << 4);
        bf1[n] = *(const short8*)(smem + 16384 + byte);
        bf2[n] = *(const short8*)(smem + 32768 + byte);
      }
#pragma unroll
      for (int m = 0; m < 4; m++)
#pragma unroll
        for (int n = 0; n < 4; n++) {
          acc_a[m][n] = __builtin_amdgcn_mfma_f32_16x16x32_bf16(af[m], bf1[n], acc_a[m][n], 0, 0, 0);
          acc_b[m][n] = __builtin_amdgcn_mfma_f32_16x16x32_bf16(af[m], bf2[n], acc_b[m][n], 0, 0, 0);
        }
    }
    __syncthreads();
  }
  // epilogue: SwiGLU -> bf16 tile in LDS, then coalesced stores
  unsigned short* ht = (unsigned short*)smem;
#pragma unroll
  for (int m = 0; m < 4; m++)
#pragma unroll
    for (int n = 0; n < 4; n++)
#pragma unroll
      for (int r = 0; r < 4; r++) {
        int row = wr + m * 16 + g * 4 + r;
        int col = wc + n * 16 + ln;
        float a = acc_a[m][n][r] + s_b1[col];
        float b = acc_b[m][n][r] + s_b2[col];
        float hv = a * (b / (1.f + __expf(-b)));
        ht[row * 128 + col] = f2bf(hv);
      }
  __syncthreads();
#pragma unroll
  for (int q = 0; q < 8; q++) {
    int idx = q * 256 + tid;
    int row = idx >> 4, chunk = idx & 15;
    short8 v = *(const short8*)(smem + idx * 16);
    *(short8*)(hout + (size_t)(row0 + row) * HDIM + col0 + chunk * 8) = v;
  }
}

// ---- GEMM2: y = h @ wp + bp ------------------------------------------------
__launch_bounds__(256, 2)
__global__ void k_gemm2(const unsigned short* __restrict__ hin,
                        const unsigned short* __restrict__ wps, const float* __restrict__ bpg,
                        const int* __restrict__ counts, const int* __restrict__ basep,
                        unsigned short* __restrict__ yout) {
  int e = blockIdx.y >> 6;
  int rt = blockIdx.y & 63;
  int cnt = counts[e];
  if (rt >= ((cnt + 127) >> 7)) return;
  int ct = blockIdx.x;              // 0..7 over D
  int row0 = basep[e] + rt * 128;
  int col0 = ct * 128;

  __shared__ char smem[32768];      // A[128][64] | Bt
  __shared__ float s_bp[128];
  int tid = threadIdx.x;
  if (tid < 128) s_bp[tid] = bpg[e * DDIM + col0 + tid];
  __syncthreads();

  int wave = tid >> 6, l = tid & 63;
  int wr = (wave >> 1) << 6, wc = (wave & 1) << 6;
  int g = l >> 4, ln = l & 15;

  int sr[4], srow[4], sxor[4];
#pragma unroll
  for (int q = 0; q < 4; q++) {
    int flat = q * 256 + tid;
    sr[q] = flat;
    int r = flat >> 3, c = flat & 7;
    srow[q] = row0 + r;
    sxor[q] = (c ^ (r & 7)) << 3;
  }

  f32x4 zero = {0.f, 0.f, 0.f, 0.f};
  f32x4 acc[4][4];
#pragma unroll
  for (int m = 0; m < 4; m++)
#pragma unroll
    for (int n = 0; n < 4; n++) acc[m][n] = zero;

  const unsigned short* wpt = wps + ((size_t)(e * 8 + ct) * 64) * 8192;

  for (int kt = 0; kt < 64; kt++) {
#pragma unroll
    for (int q = 0; q < 4; q++) {
      gl_lds16(hin + (size_t)srow[q] * HDIM + kt * 64 + sxor[q], smem + sr[q] * 16);
      gl_lds16(wpt + (size_t)kt * 8192 + sr[q] * 8, smem + 16384 + sr[q] * 16);
    }
    __syncthreads();
#pragma unroll
    for (int ks = 0; ks < 2; ks++) {
      int kb = ks * 64 + g * 16;
      short8 af[4], bf[4];
#pragma unroll
      for (int m = 0; m < 4; m++) {
        int r = wr + m * 16 + ln;
        af[m] = *(const short8*)(smem + ((r * 128 + kb) ^ ((r & 7) << 4)));
      }
#pragma unroll
      for (int n = 0; n < 4; n++) {
        int r = wc + n * 16 + ln;
        bf[n] = *(const short8*)(smem + 16384 + ((r * 128 + kb) ^ ((r & 7) << 4)));
      }
#pragma unroll
      for (int m = 0; m < 4; m++)
#pragma unroll
        for (int n = 0; n < 4; n++)
          acc[m][n] = __builtin_amdgcn_mfma_f32_16x16x32_bf16(af[m], bf[n], acc[m][n], 0, 0, 0);
    }
    __syncthreads();
  }
  unsigned short* ht = (unsigned short*)smem;
#pragma unroll
  for (int m = 0; m < 4; m++)
#pragma unroll
    for (int n = 0; n < 4; n++)
#pragma unroll
      for (int r = 0; r < 4; r++) {
        int row = wr + m * 16 + g * 4 + r;
        int col = wc + n * 16 + ln;
        ht[row * 128 + col] = f2bf(acc[m][n][r] + s_bp[col]);
      }
  __syncthreads();
#pragma unroll
  for (int q = 0; q < 8; q++) {
    int idx = q * 256 + tid;
    int row = idx >> 4, chunk = idx & 15;
    short8 v = *(const short8*)(smem + idx * 16);
    *(short8*)(yout + (size_t)(row0 + row) * DDIM + col0 + chunk * 8) = v;
  }
}

// ---- combine ---------------------------------------------------------------
__global__ void k_combine(const unsigned short* __restrict__ yv,
                          const int* __restrict__ t2r, const float* __restrict__ tkp,
                          float* __restrict__ outp) {
  int gid = blockIdx.x * 256 + threadIdx.x;
  int t = gid >> 8;
  int c4 = (gid & 255) << 2;
  int r0 = t2r[2 * t], r1 = t2r[2 * t + 1];
  float p0 = tkp[2 * t], p1 = tkp[2 * t + 1];
  ushort4v u0 = *(const ushort4v*)(yv + (size_t)r0 * DDIM + c4);
  ushort4v u1 = *(const ushort4v*)(yv + (size_t)r1 * DDIM + c4);
  float4 o;
  o.x = p0 * bf2f(u0.x) + p1 * bf2f(u1.x);
  o.y = p0 * bf2f(u0.y) + p1 * bf2f(u1.y);
  o.z = p0 * bf2f(u0.z) + p1 * bf2f(u1.z);
  o.w = p0 * bf2f(u0.w) + p1 * bf2f(u1.w);
  *(float4*)(outp + (size_t)t * DDIM + c4) = o;
}

extern "C" void kernel_launch(void* const* d_in, const int* in_sizes, int n_in,
                              void* d_out, int out_size, void* d_ws, size_t ws_size,
                              hipStream_t stream) {
  const float* x   = (const float*)d_in[0];
  const float* gw  = (const float*)d_in[1];
  const float* nwt = (const float*)d_in[2];
  const float* noi = (const float*)d_in[3];
  const float* w1  = (const float*)d_in[4];
  const float* b1  = (const float*)d_in[5];
  const float* w2  = (const float*)d_in[6];
  const float* b2  = (const float*)d_in[7];
  const float* wp  = (const float*)d_in[8];
  const float* bp  = (const float*)d_in[9];
  float* outp = (float*)d_out;
  char* ws = (char*)d_ws;

  constexpr size_t SZ_W = (size_t)EEXP * DDIM * HDIM * 2;          // 67,108,864 each
  constexpr size_t OFF_XB  = 0;
  constexpr size_t OFF_W1S = OFF_XB + (size_t)T_TOK * DDIM * 2;    // 16.8 MB
  constexpr size_t OFF_W2S = OFF_W1S + SZ_W;
  constexpr size_t OFF_WPS = OFF_W2S + SZ_W;
  constexpr size_t OFF_H   = OFF_WPS + SZ_W;
  constexpr size_t OFF_Y   = OFF_H + (size_t)RMAX * HDIM * 2;      // 142.6 MB
  constexpr size_t OFF_RT  = OFF_Y + (size_t)RMAX * DDIM * 2;      // 35.7 MB
  constexpr size_t OFF_TKI = OFF_RT + (size_t)RMAX * 4;
  constexpr size_t OFF_TKP = OFF_TKI + (size_t)T_TOK * 2 * 4;
  constexpr size_t OFF_T2R = OFF_TKP + (size_t)T_TOK * 2 * 4;
  constexpr size_t OFF_CNT = OFF_T2R + (size_t)T_TOK * 2 * 4;
  constexpr size_t OFF_BAS = OFF_CNT + 256;
  constexpr size_t OFF_CUR = OFF_BAS + 256;
  // total ~397 MB

  unsigned short* xb  = (unsigned short*)(ws + OFF_XB);
  unsigned short* w1s = (unsigned short*)(ws + OFF_W1S);
  unsigned short* w2s = (unsigned short*)(ws + OFF_W2S);
  unsigned short* wps = (unsigned short*)(ws + OFF_WPS);
  unsigned short* h   = (unsigned short*)(ws + OFF_H);
  unsigned short* y   = (unsigned short*)(ws + OFF_Y);
  int*   rowtok = (int*)(ws + OFF_RT);
  int*   tki    = (int*)(ws + OFF_TKI);
  float* tkp    = (float*)(ws + OFF_TKP);
  int*   t2r    = (int*)(ws + OFF_T2R);
  int*   counts = (int*)(ws + OFF_CNT);
  int*   basep  = (int*)(ws + OFF_BAS);
  int*   cursor = (int*)(ws + OFF_CUR);

  dim3 blk(256);
  k_convert_x<<<dim3((T_TOK * DDIM / 4) / 256), blk, 0, stream>>>(x, xb);
  k_init<<<dim3((RMAX + 255) / 256), blk, 0, stream>>>(rowtok, counts, cursor);
  k_gate<<<dim3(T_TOK / 4), blk, 0, stream>>>(x, gw, nwt, noi, tki, tkp, counts);
  k_convert_w<<<dim3(HDIM / 128, DDIM / 64, EEXP), blk, 0, stream>>>(w1, w1s, HDIM, DDIM);
  k_convert_w<<<dim3(HDIM / 128, DDIM / 64, EEXP), blk, 0, stream>>>(w2, w2s, HDIM, DDIM);
  k_convert_w<<<dim3(DDIM / 128, HDIM / 64, EEXP), blk, 0, stream>>>(wp, wps, DDIM, HDIM);
  k_prefix<<<dim3(1), dim3(64), 0, stream>>>(counts, basep);
  k_scatter<<<dim3(T_TOK / 256), blk, 0, stream>>>(tki, basep, cursor, rowtok, t2r);
  k_gemm1<<<dim3(HDIM / 128, EEXP * 64), blk, 0, stream>>>(xb, w1s, w2s, b1, b2, counts, basep, rowtok, h);
  k_gemm2<<<dim3(DDIM / 128, EEXP * 64), blk, 0, stream>>>(h, wps, bp, counts, basep, y);
  k_combine<<<dim3(T_TOK), blk, 0, stream>>>(y, t2r, tkp, outp);
  (void)in_sizes; (void)n_in; (void)out_size; (void)ws_size;
}